// Round 23
// baseline (71.576 us; speedup 1.0000x reference)
//
#include <hip/hip_runtime.h>
#include <math.h>

// No implicit contraction — the projection arithmetic below is bit-frozen
// (verified absmax 0.0 in round 17). Do not change any rounding.
#pragma clang fp contract(off)

#define C_IMG   16
#define C_LIDAR 16
#define IMG_H   376
#define IMG_W   1248
#define HW      (IMG_H * IMG_W)
#define C_OUT   (C_IMG + C_LIDAR)
#define TILE    256              // pixels per block-tile; HW % 256 == 0
#define LROW    (TILE + 2)       // stride 258: 2-way max LDS aliasing (free)

// Pass 1: (B,C,H,W) -> (B,H,W,C). Persistent grid-stride blocks, double-
// buffered LDS, software pipeline: next tile's float4 loads (1KB/inst) are
// issued before the current tile's drain. Stores: unit-stride float4
// (exact-line merging, proven WRITE_SIZE == ideal).
__global__ __launch_bounds__(256) void transpose_pipe_kernel(
    const float* __restrict__ images,   // (B, 16, H, W)
    float*       __restrict__ ws,       // (B, H, W, 16)
    int tiles_total)                    // B*HW / TILE
{
    __shared__ float lds[2][C_IMG][LROW];   // 2 x 16.5KB = 33KB

    const int t    = threadIdx.x;
    const int lane = t & 63;
    const int cofs = t >> 6;            // wave id 0..3 -> channel offset

    int tile = blockIdx.x;
    if (tile >= tiles_total) return;

    // preload tile: thread loads float4 of channel (4i+cofs), pixels 4*lane..
    float4 r0, r1, r2, r3;
    {
        long long pb = (long long)tile * TILE;
        int b = (int)(pb / HW);
        int pix = (int)(pb - (long long)b * HW);
        const float* src = images + (size_t)b * (C_IMG * HW) + pix + 4 * lane;
        r0 = *(const float4*)(src + (size_t)(0 * 4 + cofs) * HW);
        r1 = *(const float4*)(src + (size_t)(1 * 4 + cofs) * HW);
        r2 = *(const float4*)(src + (size_t)(2 * 4 + cofs) * HW);
        r3 = *(const float4*)(src + (size_t)(3 * 4 + cofs) * HW);
    }

    int p = 0;
    while (true) {
        // stage current tile into buf p
        *(float4*)&lds[p][0 * 4 + cofs][4 * lane] = r0;
        *(float4*)&lds[p][1 * 4 + cofs][4 * lane] = r1;
        *(float4*)&lds[p][2 * 4 + cofs][4 * lane] = r2;
        *(float4*)&lds[p][3 * 4 + cofs][4 * lane] = r3;

        // issue next tile's loads (in flight across the drain below)
        int next = tile + gridDim.x;
        bool hn = next < tiles_total;
        float4 n0, n1, n2, n3;
        if (hn) {
            long long pb = (long long)next * TILE;
            int b = (int)(pb / HW);
            int pix = (int)(pb - (long long)b * HW);
            const float* src = images + (size_t)b * (C_IMG * HW) + pix + 4 * lane;
            n0 = *(const float4*)(src + (size_t)(0 * 4 + cofs) * HW);
            n1 = *(const float4*)(src + (size_t)(1 * 4 + cofs) * HW);
            n2 = *(const float4*)(src + (size_t)(2 * 4 + cofs) * HW);
            n3 = *(const float4*)(src + (size_t)(3 * 4 + cofs) * HW);
        }

        __syncthreads();    // buf p fully staged

        // drain buf p: slot s = k*256+t; pixel s>>2, quad s&3; unit-stride.
        {
            long long pb = (long long)tile * TILE;
            float4* dst = (float4*)(ws + (size_t)pb * C_IMG);
            #pragma unroll
            for (int k = 0; k < 4; ++k) {
                int s  = k * 256 + t;
                int px = s >> 2;
                int q  = s & 3;
                float4 o;
                o.x = lds[p][4 * q + 0][px];
                o.y = lds[p][4 * q + 1][px];
                o.z = lds[p][4 * q + 2][px];
                o.w = lds[p][4 * q + 3][px];
                dst[s] = o;
            }
        }

        if (!hn) break;
        r0 = n0; r1 = n1; r2 = n2; r3 = n3;
        tile = next;
        p ^= 1;             // dbuf: next stage can't race an unfinished drain
    }
}

// Pass 2: 8 threads per voxel; lanes 0-3 read one float4 each of the
// SAME 64B pixel line from ws; lanes 4-7 copy vfeat. Coalesced stores.
__global__ __launch_bounds__(256) void gather_kernel(
    const float* __restrict__ vfeat,    // (N, 16)
    const int*   __restrict__ vcoord,   // (N, 4)  [b, z, y, x]
    const float* __restrict__ ws,       // (B, H, W, 16)
    const float* __restrict__ calib,    // (B, 3, 4)
    float*       __restrict__ out,      // (N, 32)
    int n_vox)
{
    int tid  = blockIdx.x * blockDim.x + threadIdx.x;
    int n    = tid >> 3;
    int lane = tid & 7;
    if (n >= n_vox) return;

    float4* ov = (float4*)(out + (size_t)n * C_OUT);

    if (lane >= 4) {
        const float4* vfr = (const float4*)(vfeat + (size_t)n * C_LIDAR);
        ov[lane] = vfr[lane - 4];
        return;
    }

    int4 c4 = ((const int4*)vcoord)[n];
    int b = c4.x, z = c4.y, y = c4.z, x = c4.w;

    // ---- bit-frozen projection (r17-verified) ----
    float px = (float)x * 0.05f;
    float py = (float)y * 0.05f + -25.6f;
    float pz = (float)z * 0.1f  + -2.0f;

    const float* P = calib + b * 12;
    float pr0 = fmaf(P[3], 1.0f, fmaf(P[2], pz, fmaf(P[1], py, fmaf(P[0], px, 0.0f))));
    float pr1 = fmaf(P[7], 1.0f, fmaf(P[6], pz, fmaf(P[5], py, fmaf(P[4], px, 0.0f))));
    float pr2 = fmaf(P[11], 1.0f, fmaf(P[10], pz, fmaf(P[9], py, fmaf(P[8], px, 0.0f))));

    float inv = 1.0f / pr2;    // CR reciprocal (XLA div->mul rewrite)
    float uf = pr0 * inv;      // plain RN mul
    float vf = pr1 * inv;

    int u = (int)uf;
    int v = (int)vf;
    // ---- end bit-frozen section ----

    bool valid = (u >= 0) & (u < IMG_W) & (v >= 0) & (v < IMG_H);
    int uc = min(max(u, 0), IMG_W - 1);
    int vc = min(max(v, 0), IMG_H - 1);

    const float4* line = (const float4*)(ws
        + ((size_t)b * HW + (size_t)vc * IMG_W + uc) * C_IMG);
    float4 g = line[lane];

    float4 r;
    r.x = valid ? g.x : 0.0f;
    r.y = valid ? g.y : 0.0f;
    r.z = valid ? g.z : 0.0f;
    r.w = valid ? g.w : 0.0f;
    ov[lane] = r;
}

// Fallback (r18 path) if workspace is too small for the transposed image.
__global__ __launch_bounds__(256) void gather_direct_kernel(
    const float* __restrict__ vfeat,
    const int*   __restrict__ vcoord,
    const float* __restrict__ images,
    const float* __restrict__ calib,
    float*       __restrict__ out,
    int n_vox)
{
    int tid  = blockIdx.x * blockDim.x + threadIdx.x;
    int n    = tid >> 3;
    int lane = tid & 7;
    if (n >= n_vox) return;

    float4* ov = (float4*)(out + (size_t)n * C_OUT);
    if (lane >= 4) {
        const float4* vfr = (const float4*)(vfeat + (size_t)n * C_LIDAR);
        ov[lane] = vfr[lane - 4];
        return;
    }

    int4 c4 = ((const int4*)vcoord)[n];
    int b = c4.x, z = c4.y, y = c4.z, x = c4.w;

    float px = (float)x * 0.05f;
    float py = (float)y * 0.05f + -25.6f;
    float pz = (float)z * 0.1f  + -2.0f;

    const float* P = calib + b * 12;
    float pr0 = fmaf(P[3], 1.0f, fmaf(P[2], pz, fmaf(P[1], py, fmaf(P[0], px, 0.0f))));
    float pr1 = fmaf(P[7], 1.0f, fmaf(P[6], pz, fmaf(P[5], py, fmaf(P[4], px, 0.0f))));
    float pr2 = fmaf(P[11], 1.0f, fmaf(P[10], pz, fmaf(P[9], py, fmaf(P[8], px, 0.0f))));

    float inv = 1.0f / pr2;
    float uf = pr0 * inv;
    float vf = pr1 * inv;
    int u = (int)uf;
    int v = (int)vf;

    bool valid = (u >= 0) & (u < IMG_W) & (v >= 0) & (v < IMG_H);
    int uc = min(max(u, 0), IMG_W - 1);
    int vc = min(max(v, 0), IMG_H - 1);

    const float* ib = images + (size_t)b * (C_IMG * HW)
                             + (size_t)vc * IMG_W + uc
                             + (size_t)(lane * 4) * HW;
    float g0 = ib[0];
    float g1 = ib[(size_t)1 * HW];
    float g2 = ib[(size_t)2 * HW];
    float g3 = ib[(size_t)3 * HW];

    float4 r;
    r.x = valid ? g0 : 0.0f;
    r.y = valid ? g1 : 0.0f;
    r.z = valid ? g2 : 0.0f;
    r.w = valid ? g3 : 0.0f;
    ov[lane] = r;
}

extern "C" void kernel_launch(void* const* d_in, const int* in_sizes, int n_in,
                              void* d_out, int out_size, void* d_ws, size_t ws_size,
                              hipStream_t stream) {
    const float* vfeat  = (const float*)d_in[0];
    const int*   vcoord = (const int*)d_in[1];
    const float* images = (const float*)d_in[2];
    const float* calib  = (const float*)d_in[3];
    float* out = (float*)d_out;

    int n_vox = in_sizes[1] / 4;            // voxel_coords is (N, 4)
    int total_pixels = in_sizes[2] / C_IMG; // B * H * W
    size_t ws_needed = (size_t)total_pixels * C_IMG * sizeof(float);

    long long total = (long long)n_vox * 8;
    dim3 block(256);
    dim3 ggrid((unsigned)((total + 255) / 256));

    if (ws_size >= ws_needed && (total_pixels % TILE) == 0) {
        float* ws = (float*)d_ws;
        int tiles_total = total_pixels / TILE;     // 7332
        int tgrid = tiles_total < 2048 ? tiles_total : 2048;
        transpose_pipe_kernel<<<dim3(tgrid), block, 0, stream>>>(images, ws, tiles_total);
        gather_kernel<<<ggrid, block, 0, stream>>>(vfeat, vcoord, ws, calib, out, n_vox);
    } else {
        gather_direct_kernel<<<ggrid, block, 0, stream>>>(vfeat, vcoord, images, calib, out, n_vox);
    }
}

// Round 25
// 61.831 us; speedup vs baseline: 1.1576x; 1.1576x over previous
//
#include <hip/hip_runtime.h>
#include <math.h>

// No implicit contraction — the projection arithmetic below is bit-frozen
// (verified absmax 0.0 in round 17). Do not change any rounding.
#pragma clang fp contract(off)

#define C_IMG   16
#define C_LIDAR 16
#define IMG_H   376
#define IMG_W   1248
#define HW      (IMG_H * IMG_W)
#define C_OUT   (C_IMG + C_LIDAR)
#define TPIX    64               // pixels per wave-tile; HW % 64 == 0
#define LROW    (TPIX + 2)       // +2 pad: stage/drain aliasing <=2-way (free)

// clang-native 4-float vector: accepted by __builtin_nontemporal_*
typedef float v4f __attribute__((ext_vector_type(4)));

// Pass 1: (B,C,H,W) -> (B,H,W,C) via small LDS tiles.
// ws stores are NONTEMPORAL — ws (117MB, read-once) must not allocate in L3,
// or it evicts the 120MB image set mid-kernel and across replays
// (r19-r23: all transpose variants stuck at ~1.65 TB/s HBM write).
__global__ __launch_bounds__(256) void transpose_lds_kernel(
    const float* __restrict__ images,   // (B, 16, H, W)
    float*       __restrict__ ws,       // (B, H, W, 16)
    int tiles_total)                    // B*HW / TPIX
{
    __shared__ float lds[4][C_IMG][LROW];   // 4 waves x 4.2KB = 16.9KB/block

    int wv   = threadIdx.x >> 6;
    int lane = threadIdx.x & 63;
    int tile = blockIdx.x * 4 + wv;
    if (tile >= tiles_total) return;

    long long pixbase = (long long)tile * TPIX;  // batch-aligned: HW%TPIX==0
    int b   = (int)(pixbase / HW);
    int pix = (int)(pixbase - (long long)b * HW);

    const float* src = images + (size_t)b * (C_IMG * HW) + pix;

    // stage: one dword per channel per lane (cached loads: images stay in L3)
    #pragma unroll
    for (int c = 0; c < C_IMG; ++c)
        lds[wv][c][lane] = src[(size_t)c * HW + lane];

    // wave-internal LDS fence (per-wave tile, no cross-wave sharing)
    asm volatile("s_waitcnt lgkmcnt(0)" ::: "memory");

    // drain: float4 slot s = k*64+lane; pixel p = s>>2, quad q = s&3;
    // unit-stride nontemporal stores (exact-line merging, no L3 allocation).
    v4f* dst = (v4f*)(ws + (size_t)pixbase * C_IMG);
    #pragma unroll
    for (int k = 0; k < (TPIX * 4 / 64); ++k) {   // 4 iterations
        int s = k * 64 + lane;
        int p = s >> 2;
        int q = s & 3;
        v4f o;
        o.x = lds[wv][4 * q + 0][p];
        o.y = lds[wv][4 * q + 1][p];
        o.z = lds[wv][4 * q + 2][p];
        o.w = lds[wv][4 * q + 3][p];
        __builtin_nontemporal_store(o, &dst[s]);
    }
}

// Pass 2: 8 threads per voxel; lanes 0-3 read one v4f each of the SAME 64B
// pixel line from ws (nt loads: read-once, don't pollute L3); lanes 4-7 copy
// vfeat. out stores nontemporal (never re-read).
__global__ __launch_bounds__(256) void gather_kernel(
    const float* __restrict__ vfeat,    // (N, 16)
    const int*   __restrict__ vcoord,   // (N, 4)  [b, z, y, x]
    const float* __restrict__ ws,       // (B, H, W, 16)
    const float* __restrict__ calib,    // (B, 3, 4)
    float*       __restrict__ out,      // (N, 32)
    int n_vox)
{
    int tid  = blockIdx.x * blockDim.x + threadIdx.x;
    int n    = tid >> 3;
    int lane = tid & 7;
    if (n >= n_vox) return;

    v4f* ov = (v4f*)(out + (size_t)n * C_OUT);

    if (lane >= 4) {
        const v4f* vfr = (const v4f*)(vfeat + (size_t)n * C_LIDAR);
        v4f f = vfr[lane - 4];
        __builtin_nontemporal_store(f, &ov[lane]);
        return;
    }

    int4 c4 = ((const int4*)vcoord)[n];
    int b = c4.x, z = c4.y, y = c4.z, x = c4.w;

    // ---- bit-frozen projection (r17-verified) ----
    float px = (float)x * 0.05f;
    float py = (float)y * 0.05f + -25.6f;
    float pz = (float)z * 0.1f  + -2.0f;

    const float* P = calib + b * 12;
    float pr0 = fmaf(P[3], 1.0f, fmaf(P[2], pz, fmaf(P[1], py, fmaf(P[0], px, 0.0f))));
    float pr1 = fmaf(P[7], 1.0f, fmaf(P[6], pz, fmaf(P[5], py, fmaf(P[4], px, 0.0f))));
    float pr2 = fmaf(P[11], 1.0f, fmaf(P[10], pz, fmaf(P[9], py, fmaf(P[8], px, 0.0f))));

    float inv = 1.0f / pr2;    // CR reciprocal (XLA div->mul rewrite)
    float uf = pr0 * inv;      // plain RN mul
    float vf = pr1 * inv;

    int u = (int)uf;
    int v = (int)vf;
    // ---- end bit-frozen section ----

    bool valid = (u >= 0) & (u < IMG_W) & (v >= 0) & (v < IMG_H);
    int uc = min(max(u, 0), IMG_W - 1);
    int vc = min(max(v, 0), IMG_H - 1);

    const v4f* line = (const v4f*)(ws
        + ((size_t)b * HW + (size_t)vc * IMG_W + uc) * C_IMG);
    v4f g = __builtin_nontemporal_load(&line[lane]);

    v4f r;
    r.x = valid ? g.x : 0.0f;
    r.y = valid ? g.y : 0.0f;
    r.z = valid ? g.z : 0.0f;
    r.w = valid ? g.w : 0.0f;
    __builtin_nontemporal_store(r, &ov[lane]);
}

// Fallback (r18 path) if workspace is too small for the transposed image.
__global__ __launch_bounds__(256) void gather_direct_kernel(
    const float* __restrict__ vfeat,
    const int*   __restrict__ vcoord,
    const float* __restrict__ images,
    const float* __restrict__ calib,
    float*       __restrict__ out,
    int n_vox)
{
    int tid  = blockIdx.x * blockDim.x + threadIdx.x;
    int n    = tid >> 3;
    int lane = tid & 7;
    if (n >= n_vox) return;

    float4* ov = (float4*)(out + (size_t)n * C_OUT);
    if (lane >= 4) {
        const float4* vfr = (const float4*)(vfeat + (size_t)n * C_LIDAR);
        ov[lane] = vfr[lane - 4];
        return;
    }

    int4 c4 = ((const int4*)vcoord)[n];
    int b = c4.x, z = c4.y, y = c4.z, x = c4.w;

    float px = (float)x * 0.05f;
    float py = (float)y * 0.05f + -25.6f;
    float pz = (float)z * 0.1f  + -2.0f;

    const float* P = calib + b * 12;
    float pr0 = fmaf(P[3], 1.0f, fmaf(P[2], pz, fmaf(P[1], py, fmaf(P[0], px, 0.0f))));
    float pr1 = fmaf(P[7], 1.0f, fmaf(P[6], pz, fmaf(P[5], py, fmaf(P[4], px, 0.0f))));
    float pr2 = fmaf(P[11], 1.0f, fmaf(P[10], pz, fmaf(P[9], py, fmaf(P[8], px, 0.0f))));

    float inv = 1.0f / pr2;
    float uf = pr0 * inv;
    float vf = pr1 * inv;
    int u = (int)uf;
    int v = (int)vf;

    bool valid = (u >= 0) & (u < IMG_W) & (v >= 0) & (v < IMG_H);
    int uc = min(max(u, 0), IMG_W - 1);
    int vc = min(max(v, 0), IMG_H - 1);

    const float* ib = images + (size_t)b * (C_IMG * HW)
                             + (size_t)vc * IMG_W + uc
                             + (size_t)(lane * 4) * HW;
    float g0 = ib[0];
    float g1 = ib[(size_t)1 * HW];
    float g2 = ib[(size_t)2 * HW];
    float g3 = ib[(size_t)3 * HW];

    float4 r;
    r.x = valid ? g0 : 0.0f;
    r.y = valid ? g1 : 0.0f;
    r.z = valid ? g2 : 0.0f;
    r.w = valid ? g3 : 0.0f;
    ov[lane] = r;
}

extern "C" void kernel_launch(void* const* d_in, const int* in_sizes, int n_in,
                              void* d_out, int out_size, void* d_ws, size_t ws_size,
                              hipStream_t stream) {
    const float* vfeat  = (const float*)d_in[0];
    const int*   vcoord = (const int*)d_in[1];
    const float* images = (const float*)d_in[2];
    const float* calib  = (const float*)d_in[3];
    float* out = (float*)d_out;

    int n_vox = in_sizes[1] / 4;            // voxel_coords is (N, 4)
    int total_pixels = in_sizes[2] / C_IMG; // B * H * W
    size_t ws_needed = (size_t)total_pixels * C_IMG * sizeof(float);

    long long total = (long long)n_vox * 8;
    dim3 block(256);
    dim3 ggrid((unsigned)((total + 255) / 256));

    if (ws_size >= ws_needed && (total_pixels % TPIX) == 0) {
        float* ws = (float*)d_ws;
        int tiles_total = total_pixels / TPIX;
        dim3 tgrid((unsigned)((tiles_total + 3) / 4));
        transpose_lds_kernel<<<tgrid, block, 0, stream>>>(images, ws, tiles_total);
        gather_kernel<<<ggrid, block, 0, stream>>>(vfeat, vcoord, ws, calib, out, n_vox);
    } else {
        gather_direct_kernel<<<ggrid, block, 0, stream>>>(vfeat, vcoord, images, calib, out, n_vox);
    }
}